// Round 1
// baseline (983.743 us; speedup 1.0000x reference)
//
#include <hip/hip_runtime.h>
#include <math.h>

// ---- problem constants ----
#define TOKENS   16384      // B*T
#define TPB      4096       // tokens per batch row (T)
#define D_DIM    2048       // hidden / output dim (N of GEMM)
#define K_DIM    2048       // H*2*E (K of GEMM)
#define E_DIM    256
#define TS_SIZE  100000
#define VOCAB_M1 50256

typedef __bf16 bf16x8 __attribute__((ext_vector_type(8)));
typedef float  f32x4  __attribute__((ext_vector_type(4)));

#define GAS __attribute__((address_space(1)))
#define LAS __attribute__((address_space(3)))

__device__ __forceinline__ int clampid(int x) {
    return x < 0 ? 0 : (x > VOCAB_M1 ? VOCAB_M1 : x);
}

// ---------------------------------------------------------------------------
// Kernel 1: hash + table gather -> E[16384][2048] in bf16.
// One block per token; thread handles 8 consecutive floats (one 16B bf16 store).
// ---------------------------------------------------------------------------
__global__ __launch_bounds__(256) void gather_kernel(
    const float* __restrict__ t2, const float* __restrict__ t3,
    const int* __restrict__ ids, __bf16* __restrict__ E)
{
    const int t   = blockIdx.x;
    const int b   = t >> 12;          // / TPB
    const int pos = t & (TPB - 1);
    const int* row = ids + b * TPB;
    int id0 = clampid(row[pos]);
    int id1 = (pos >= 1) ? clampid(row[pos - 1]) : 0;
    int id2 = (pos >= 2) ? clampid(row[pos - 2]) : 0;
    // products stay < 2^31 (50256*40009 = 2.01e9), xor of non-negatives is non-negative
    int h2 = (id0 * 20011) ^ (id1 * 30011);
    int h3 = h2 ^ (id2 * 40009);
    int i2 = h2 % TS_SIZE;
    int i3 = h3 % TS_SIZE;

    const int k = threadIdx.x * 8;    // 0..2047, 8 elems per thread
    const float* src;
    if (k < 1024) {                   // e2 half: k = h*256 + e
        src = t2 + ((size_t)(k >> 8) * TS_SIZE + (size_t)i2) * E_DIM + (k & 255);
    } else {                          // e3 half
        int kk = k - 1024;
        src = t3 + ((size_t)(kk >> 8) * TS_SIZE + (size_t)i3) * E_DIM + (kk & 255);
    }
    float4 f0 = *(const float4*)src;
    float4 f1 = *(const float4*)(src + 4);
    bf16x8 o;
    o[0] = (__bf16)f0.x; o[1] = (__bf16)f0.y; o[2] = (__bf16)f0.z; o[3] = (__bf16)f0.w;
    o[4] = (__bf16)f1.x; o[5] = (__bf16)f1.y; o[6] = (__bf16)f1.z; o[7] = (__bf16)f1.w;
    *(bf16x8*)(E + (size_t)t * K_DIM + k) = o;
}

// ---------------------------------------------------------------------------
// Kernel 2: Wv fp32 [2048][2048] -> bf16 (same layout, K-contiguous = B^T GEMM input)
// ---------------------------------------------------------------------------
__global__ __launch_bounds__(256) void convert_wv(
    const float* __restrict__ Wv, __bf16* __restrict__ Wb)
{
    const int i = (blockIdx.x * 256 + threadIdx.x) * 8;
    float4 f0 = *(const float4*)(Wv + i);
    float4 f1 = *(const float4*)(Wv + i + 4);
    bf16x8 o;
    o[0] = (__bf16)f0.x; o[1] = (__bf16)f0.y; o[2] = (__bf16)f0.z; o[3] = (__bf16)f0.w;
    o[4] = (__bf16)f1.x; o[5] = (__bf16)f1.y; o[6] = (__bf16)f1.z; o[7] = (__bf16)f1.w;
    *(bf16x8*)(Wb + i) = o;
}

// ---------------------------------------------------------------------------
// Kernel 3: GEMM  C[m][n] = sum_k A[m][k] * B[n][k]   (both K-contiguous, bf16)
// m97 structure: 128x128 tile, BK=64, 256 threads = 4 waves (2x2 of 64x64),
// 16x16x32 bf16 MFMA 4x4 per wave, global_load_lds width=16, 2-barrier K-loop.
// C written fp32 to d_out.
// ---------------------------------------------------------------------------
__global__ __launch_bounds__(256) void gemm_kernel(
    const __bf16* __restrict__ A, const __bf16* __restrict__ B,
    float* __restrict__ C)
{
    __shared__ __bf16 As[128 * 64];   // 16 KB, row-major [row][64], no padding
    __shared__ __bf16 Bs[128 * 64];   // (global_load_lds requires lane-contiguous dest)

    const int tid   = threadIdx.x;
    const int mBase = blockIdx.y * 128;
    const int nBase = blockIdx.x * 128;
    const int lane  = tid & 63;
    const int wave  = tid >> 6;
    const int wm    = (wave >> 1) * 64;   // wave row offset in tile
    const int wn    = (wave & 1) * 64;    // wave col offset in tile
    const int lm    = lane & 15;
    const int quad  = lane >> 4;
    const int sr    = tid >> 3;           // staging row within 32-row group
    const int sc    = (tid & 7) * 8;      // staging col (elements)

    f32x4 acc[4][4];
    const f32x4 zero = {0.f, 0.f, 0.f, 0.f};
#pragma unroll
    for (int i = 0; i < 4; ++i)
#pragma unroll
        for (int j = 0; j < 4; ++j) acc[i][j] = zero;

    const __bf16* aPtr = A + (size_t)mBase * K_DIM;
    const __bf16* bPtr = B + (size_t)nBase * K_DIM;

    for (int k0 = 0; k0 < K_DIM; k0 += 64) {
        // stage A[128][64] + B[128][64]: 4 calls each, 256 thr x 16B = 4KB/call
        // LDS byte offset = c*4096 + tid*16  -> wave-uniform base + lane*16  (ok)
#pragma unroll
        for (int c = 0; c < 4; ++c) {
            const int row = c * 32 + sr;
            __builtin_amdgcn_global_load_lds(
                (const GAS void*)(aPtr + (size_t)row * K_DIM + k0 + sc),
                (LAS void*)(&As[row * 64 + sc]), 16, 0, 0);
            __builtin_amdgcn_global_load_lds(
                (const GAS void*)(bPtr + (size_t)row * K_DIM + k0 + sc),
                (LAS void*)(&Bs[row * 64 + sc]), 16, 0, 0);
        }
        __syncthreads();   // drains vmcnt -> staged data visible

#pragma unroll
        for (int kk = 0; kk < 64; kk += 32) {
            bf16x8 af[4], bv[4];
#pragma unroll
            for (int i = 0; i < 4; ++i)
                af[i] = *(const bf16x8*)&As[(wm + i * 16 + lm) * 64 + kk + quad * 8];
#pragma unroll
            for (int j = 0; j < 4; ++j)
                bv[j] = *(const bf16x8*)&Bs[(wn + j * 16 + lm) * 64 + kk + quad * 8];
#pragma unroll
            for (int i = 0; i < 4; ++i)
#pragma unroll
                for (int j = 0; j < 4; ++j)
                    acc[i][j] = __builtin_amdgcn_mfma_f32_16x16x32_bf16(
                        af[i], bv[j], acc[i][j], 0, 0, 0);
        }
        __syncthreads();
    }

    // C/D layout (m89-verified): col = lane&15, row = (lane>>4)*4 + reg
#pragma unroll
    for (int i = 0; i < 4; ++i) {
#pragma unroll
        for (int r = 0; r < 4; ++r) {
            const int m = mBase + wm + i * 16 + quad * 4 + r;
            float* crow = C + (size_t)m * D_DIM + nBase + wn + lm;
#pragma unroll
            for (int j = 0; j < 4; ++j)
                crow[j * 16] = acc[i][j][r];
        }
    }
}

// ---------------------------------------------------------------------------
// Kernel 4: fused epilogue. One block per token row.
//   Sh = sum(h^2), Sv = sum(v^2), Sd = sum(h*gh * v*gv)
//   gate = sigmoid( signed_sqrt( Sd * rsqrt(Sh/D+eps) * rsqrt(Sv/D+eps) / sqrt(D) ) )
//   out = gate * v   (in place over d_out; v kept in registers)
// ---------------------------------------------------------------------------
__global__ __launch_bounds__(256) void epilogue_kernel(
    const float* __restrict__ hidden, const float* __restrict__ gh,
    const float* __restrict__ gv, float* __restrict__ out)
{
    const int t   = blockIdx.x;
    const int tid = threadIdx.x;
    const int kb  = tid * 8;
    const size_t base = (size_t)t * D_DIM + kb;

    float4 h0 = *(const float4*)(hidden + base);
    float4 h1 = *(const float4*)(hidden + base + 4);
    float4 v0 = *(const float4*)(out + base);
    float4 v1 = *(const float4*)(out + base + 4);
    float4 a0 = *(const float4*)(gh + kb);
    float4 a1 = *(const float4*)(gh + kb + 4);
    float4 b0 = *(const float4*)(gv + kb);
    float4 b1 = *(const float4*)(gv + kb + 4);

    float sh = h0.x*h0.x + h0.y*h0.y + h0.z*h0.z + h0.w*h0.w
             + h1.x*h1.x + h1.y*h1.y + h1.z*h1.z + h1.w*h1.w;
    float sv = v0.x*v0.x + v0.y*v0.y + v0.z*v0.z + v0.w*v0.w
             + v1.x*v1.x + v1.y*v1.y + v1.z*v1.z + v1.w*v1.w;
    float sd = h0.x*a0.x*v0.x*b0.x + h0.y*a0.y*v0.y*b0.y
             + h0.z*a0.z*v0.z*b0.z + h0.w*a0.w*v0.w*b0.w
             + h1.x*a1.x*v1.x*b1.x + h1.y*a1.y*v1.y*b1.y
             + h1.z*a1.z*v1.z*b1.z + h1.w*a1.w*v1.w*b1.w;

    // wave (64-lane) butterfly reduce
#pragma unroll
    for (int off = 32; off > 0; off >>= 1) {
        sh += __shfl_down(sh, off, 64);
        sv += __shfl_down(sv, off, 64);
        sd += __shfl_down(sd, off, 64);
    }
    __shared__ float red[12];
    const int wave = tid >> 6, lane = tid & 63;
    if (lane == 0) { red[wave] = sh; red[4 + wave] = sv; red[8 + wave] = sd; }
    __syncthreads();
    const float SH = red[0] + red[1] + red[2] + red[3];
    const float SV = red[4] + red[5] + red[6] + red[7];
    const float SD = red[8] + red[9] + red[10] + red[11];

    const float eps = 1.1920929e-7f;              // finfo(float32).eps
    const float rh  = rsqrtf(SH * (1.f / D_DIM) + eps);
    const float rv  = rsqrtf(SV * (1.f / D_DIM) + eps);
    float g = SD * rh * rv * 0.022097086912079608f;  // 1/sqrt(2048)
    const float sgn = (g > 0.f) ? 1.f : ((g < 0.f) ? -1.f : 0.f);
    const float gm  = sqrtf(fmaxf(fabsf(g), 1e-6f)) * sgn;
    const float gate = 1.f / (1.f + expf(-gm));

    float4 o0 = make_float4(gate * v0.x, gate * v0.y, gate * v0.z, gate * v0.w);
    float4 o1 = make_float4(gate * v1.x, gate * v1.y, gate * v1.z, gate * v1.w);
    *(float4*)(out + base)     = o0;
    *(float4*)(out + base + 4) = o1;
}

// ---------------------------------------------------------------------------
extern "C" void kernel_launch(void* const* d_in, const int* in_sizes, int n_in,
                              void* d_out, int out_size, void* d_ws, size_t ws_size,
                              hipStream_t stream) {
    const float* hidden = (const float*)d_in[0];
    const float* t2     = (const float*)d_in[1];
    const float* t3     = (const float*)d_in[2];
    const float* Wv     = (const float*)d_in[3];
    const float* gh     = (const float*)d_in[4];
    const float* gv     = (const float*)d_in[5];
    const int*   ids    = (const int*)d_in[6];
    float* out = (float*)d_out;

    // workspace: E bf16 [16384*2048] (64 MB) + Wb bf16 [2048*2048] (8 MB)
    __bf16* E  = (__bf16*)d_ws;
    __bf16* Wb = (__bf16*)((char*)d_ws + (size_t)TOKENS * K_DIM * sizeof(__bf16));

    gather_kernel<<<TOKENS, 256, 0, stream>>>(t2, t3, ids, E);
    convert_wv<<<(D_DIM * K_DIM) / (256 * 8), 256, 0, stream>>>(Wv, Wb);
    gemm_kernel<<<dim3(D_DIM / 128, TOKENS / 128), 256, 0, stream>>>(E, Wb, out);
    epilogue_kernel<<<TOKENS, 256, 0, stream>>>(hidden, gh, gv, out);
}